// Round 5
// baseline (473.816 us; speedup 1.0000x reference)
//
#include <hip/hip_runtime.h>
#include <math.h>

#define N_ 8
#define L_ 1024
#define H_ 16
#define E_ 1024
#define D_ 64

typedef __bf16 bf16x8 __attribute__((ext_vector_type(8)));
typedef __bf16 bf16x4 __attribute__((ext_vector_type(4)));
typedef float  f32x4  __attribute__((ext_vector_type(4)));

#define MFMA16(a, b, c) __builtin_amdgcn_mfma_f32_16x16x32_bf16((a), (b), (c), 0, 0, 0)

// exp(s/32) == exp2(s * KSCALE) with KSCALE folded into K at projection time.
#define KSCALE 0.04508422002778011f   // log2(e)/32

// ---------------------------------------------------------------------------
// prep: convert Wo (1M) and Erel (64K) f32 -> bf16 scratch.
// ---------------------------------------------------------------------------
__global__ __launch_bounds__(256) void prep_kernel(
    const float* __restrict__ Wo, const float* __restrict__ Erel,
    __bf16* __restrict__ wobf, __bf16* __restrict__ erbf)
{
    const int idx = blockIdx.x * 256 + threadIdx.x;
    const float* src;
    __bf16* dst;
    int off;
    if (blockIdx.x < 1024) { src = Wo;   dst = wobf; off = idx * 4; }
    else                   { src = Erel; dst = erbf; off = (idx - 1024 * 256) * 4; }
    const float4 f = *(const float4*)(src + off);
    bf16x4 h;
    h[0] = (__bf16)f.x; h[1] = (__bf16)f.y; h[2] = (__bf16)f.z; h[3] = (__bf16)f.w;
    *(bf16x4*)(dst + off) = h;
}

// ---------------------------------------------------------------------------
// qkv: x viewed as (131072 x 64) row-major (rows m=(n,l,h)); q/k/v = x @ W^T + b
// K is pre-scaled by KSCALE (softmax base-2 fold). Epilogue goes through an
// LDS transpose so global stores are coalesced b128 (was 48 scalar 2B stores).
// ---------------------------------------------------------------------------
__global__ __launch_bounds__(256) void qkv_kernel(
    const float* __restrict__ x,
    const float* __restrict__ Wq, const float* __restrict__ bq,
    const float* __restrict__ Wk, const float* __restrict__ bk,
    const float* __restrict__ Wv, const float* __restrict__ bv,
    __bf16* __restrict__ qo, __bf16* __restrict__ ko, __bf16* __restrict__ vo)
{
    const int t = threadIdx.x, w = t >> 6, lane = t & 63;
    const int quad = lane >> 4, l16 = lane & 15;
    const int m0 = blockIdx.x * 64;

    __shared__ __bf16 xs[64][72];
    __shared__ __bf16 wls[3][64][72];

    #pragma unroll
    for (int i = 0; i < 4; ++i) {
        const int idx = t + i * 256, row = idx >> 4, c4 = idx & 15;
        {
            const float4 f = *(const float4*)(x + (size_t)(m0 + row) * 64 + c4 * 4);
            bf16x4 hh; hh[0]=(__bf16)f.x; hh[1]=(__bf16)f.y; hh[2]=(__bf16)f.z; hh[3]=(__bf16)f.w;
            *(bf16x4*)&xs[row][c4 * 4] = hh;
        }
        {
            const float4 f = *(const float4*)(Wq + (size_t)row * 64 + c4 * 4);
            bf16x4 hh; hh[0]=(__bf16)f.x; hh[1]=(__bf16)f.y; hh[2]=(__bf16)f.z; hh[3]=(__bf16)f.w;
            *(bf16x4*)&wls[0][row][c4 * 4] = hh;
        }
        {
            const float4 f = *(const float4*)(Wk + (size_t)row * 64 + c4 * 4);
            bf16x4 hh; hh[0]=(__bf16)f.x; hh[1]=(__bf16)f.y; hh[2]=(__bf16)f.z; hh[3]=(__bf16)f.w;
            *(bf16x4*)&wls[1][row][c4 * 4] = hh;
        }
        {
            const float4 f = *(const float4*)(Wv + (size_t)row * 64 + c4 * 4);
            bf16x4 hh; hh[0]=(__bf16)f.x; hh[1]=(__bf16)f.y; hh[2]=(__bf16)f.z; hh[3]=(__bf16)f.w;
            *(bf16x4*)&wls[2][row][c4 * 4] = hh;
        }
    }
    __syncthreads();

    bf16x8 a[2];
    a[0] = *(const bf16x8*)&xs[w * 16 + l16][quad * 8];
    a[1] = *(const bf16x8*)&xs[w * 16 + l16][32 + quad * 8];

    f32x4 acc[12];
    const f32x4 zero4 = {0.f, 0.f, 0.f, 0.f};
    #pragma unroll
    for (int nt = 0; nt < 12; ++nt) acc[nt] = zero4;

    #pragma unroll
    for (int nt = 0; nt < 12; ++nt) {
        const int sel = nt >> 2, dt = nt & 3;
        #pragma unroll
        for (int c = 0; c < 2; ++c) {
            const bf16x8 b = *(const bf16x8*)&wls[sel][dt * 16 + l16][c * 32 + quad * 8];
            acc[nt] = MFMA16(a[c], b, acc[nt]);
        }
    }
    __syncthreads();   // wls reads done -> reuse as transpose staging

    // epilogue: C-frags -> ts[64][208] (cols: sel*64 + d), then coalesced dump
    __bf16* ts = &wls[0][0][0];
    const float* bias[3] = {bq, bk, bv};
    __bf16* outp[3] = {qo, ko, vo};
    #pragma unroll
    for (int nt = 0; nt < 12; ++nt) {
        const int sel = nt >> 2, dt = nt & 3;
        const float bb = bias[sel][dt * 16 + l16];
        const float scl = (sel == 1) ? KSCALE : 1.0f;
        #pragma unroll
        for (int r = 0; r < 4; ++r)
            ts[(size_t)(w * 16 + quad * 4 + r) * 208 + sel * 64 + dt * 16 + l16] =
                (__bf16)((acc[nt][r] + bb) * scl);
    }
    __syncthreads();
    #pragma unroll
    for (int sel = 0; sel < 3; ++sel)
        #pragma unroll
        for (int i = 0; i < 2; ++i) {
            const int idx = t * 2 + i, row = idx >> 3, c = idx & 7;
            *(float4*)(outp[sel] + (size_t)(m0 + row) * 64 + c * 8) =
                *(const float4*)&ts[(size_t)row * 208 + sel * 64 + c * 8];
        }
}

// ---------------------------------------------------------------------------
// vtr: v (n,l,h,d) -> vtr (n,h,d,l)  [64x64 tiles through LDS]
// ---------------------------------------------------------------------------
__global__ __launch_bounds__(256) void vtr_kernel(
    const __bf16* __restrict__ v, __bf16* __restrict__ vt)
{
    const int bid = blockIdx.x;
    const int lt = bid & 15, h = (bid >> 4) & 15, n = bid >> 8;
    const int l0 = lt * 64;
    const int t = threadIdx.x;
    __shared__ __bf16 ls[64][72];    // [d][l]

    const int lrow = t & 63, c0 = t >> 6;
    #pragma unroll
    for (int i = 0; i < 2; ++i) {
        const int c = c0 + i * 4;
        union { float4 f; __bf16 hv[8]; } u;
        u.f = *(const float4*)(v + ((size_t)(n * L_ + l0 + lrow) * H_ + h) * D_ + c * 8);
        #pragma unroll
        for (int j = 0; j < 8; ++j) ls[c * 8 + j][lrow] = u.hv[j];
    }
    __syncthreads();
    const int drow0 = t >> 3, lc = t & 7;
    #pragma unroll
    for (int i = 0; i < 2; ++i) {
        const int d = drow0 + i * 32;
        *(float4*)(vt + ((size_t)(n * H_ + h) * D_ + d) * L_ + l0 + lc * 8) =
            *(const float4*)&ls[d][lc * 8];
    }
}

// ---------------------------------------------------------------------------
// attn: 512 threads (8 waves), 128 q rows per block, computed transposed
// (lane's l16 = q). Fixed-base softmax: K pre-scaled by log2(e)/32, so
// P = exp2(S') with NO running max / rescale; per-lane esum accumulated
// across all tiles, single cross-lane reduce at the epilogue. Double-buffered
// K/V; V comes pre-transposed (vtr) so staging is b128 both ways.
// ---------------------------------------------------------------------------
__global__ __launch_bounds__(512, 4) void attn_kernel(
    const __bf16* __restrict__ qbf, const __bf16* __restrict__ kbf,
    const __bf16* __restrict__ vtrb, const __bf16* __restrict__ erbf,
    __bf16* __restrict__ attnA)
{
    const int bid = blockIdx.x;
    // XCD swizzle: all 8 q-tiles of one (n,h) share bid%8 -> same XCD L2.
    const int p  = (bid & 7) | ((bid >> 6) << 3);
    const int qt = (bid >> 3) & 7;
    const int h = p & 15, n = p >> 4;
    const int q0 = qt * 128;
    const int t = threadIdx.x, w = t >> 6, lane = t & 63;
    const int quad = lane >> 4, l16 = lane & 15;

    __shared__ __bf16 ks[2][64][72];  // K tile row-major (key, d)
    __shared__ __bf16 vt[2][64][72];  // V^T tile (d, key)
    __shared__ __bf16 ps[128][72];    // exp-P / rel / epilogue (wave-private rows)

    const int qw0 = q0 + w * 16;
    const size_t qrowoff = ((size_t)(n * L_ + qw0 + l16) * H_ + h) * D_;
    const bf16x8 qa0 = *(const bf16x8*)(qbf + qrowoff + quad * 8);
    const bf16x8 qa1 = *(const bf16x8*)(qbf + qrowoff + 32 + quad * 8);

    const __bf16* kbase = kbf + ((size_t)n * L_ * H_ + h) * D_;        // rows l
    const __bf16* vbase = vtrb + ((size_t)(n * H_ + h) * D_) * L_;     // rows d
    const int srow = t >> 3, sc8 = (t & 7) * 8;   // one float4 per thread

    // tile 0 -> buf 0; tile 1 -> regs
    float4 kreg = *(const float4*)(kbase + (size_t)srow * 1024 + sc8);
    float4 vreg = *(const float4*)(vbase + (size_t)srow * 1024 + sc8);
    *(float4*)&ks[0][srow][sc8] = kreg;
    *(float4*)&vt[0][srow][sc8] = vreg;
    kreg = *(const float4*)(kbase + 64 * 1024 + (size_t)srow * 1024 + sc8);
    vreg = *(const float4*)(vbase + 64 + (size_t)srow * 1024 + sc8);
    __syncthreads();

    const f32x4 zero4 = {0.f, 0.f, 0.f, 0.f};
    f32x4 Os[4], Or[4];
    #pragma unroll
    for (int nt = 0; nt < 4; ++nt) { Os[nt] = zero4; Or[nt] = zero4; }
    float esum = 0.f;

    for (int kt = 0; kt < 16; ++kt) {
        const int cur = kt & 1;
        if (kt < 15) {
            *(float4*)&ks[cur ^ 1][srow][sc8] = kreg;
            *(float4*)&vt[cur ^ 1][srow][sc8] = vreg;
            if (kt < 14) {
                kreg = *(const float4*)(kbase + (size_t)(kt + 2) * 64 * 1024
                                        + (size_t)srow * 1024 + sc8);
                vreg = *(const float4*)(vbase + (kt + 2) * 64
                                        + (size_t)srow * 1024 + sc8);
            }
        }

        // ---- S'^T = K' Q^T (K pre-scaled by log2e/32) ----
        f32x4 sc[4];
        #pragma unroll
        for (int nt = 0; nt < 4; ++nt) {
            f32x4 acc = zero4;
            acc = MFMA16(*(const bf16x8*)&ks[cur][nt * 16 + l16][quad * 8], qa0, acc);
            acc = MFMA16(*(const bf16x8*)&ks[cur][nt * 16 + l16][32 + quad * 8], qa1, acc);
            sc[nt] = acc;
        }

        // ---- fixed-base exp + deferred lsum; pack exp-P to ps ----
        #pragma unroll
        for (int nt = 0; nt < 4; ++nt) {
            bf16x4 pk;
            #pragma unroll
            for (int r = 0; r < 4; ++r) {
                const float e = exp2f(sc[nt][r]);
                esum += e;
                pk[r] = (__bf16)e;
            }
            *(bf16x4*)&ps[w * 16 + l16][nt * 16 + quad * 4] = pk;
        }

        // ---- rel prefetch (Erel frags into regs, consumed after Os-PV) ----
        const bool dorel = (kt * 64 <= qw0 + 15);
        const int tb = kt * 64 + 1008 - qw0;
        bf16x8 e0[5], e1[5];
        if (dorel) {
            #pragma unroll
            for (int st = 0; st < 5; ++st) {
                int tr = tb + st * 16 + l16;
                tr = tr > 1023 ? 1023 : tr;
                const __bf16* er = erbf + (size_t)tr * 64;
                e0[st] = *(const bf16x8*)(er + quad * 8);
                e1[st] = *(const bf16x8*)(er + 32 + quad * 8);
            }
        }

        // ---- out^T += V^T P^T ----
        {
            const bf16x8 pb0 = *(const bf16x8*)&ps[w * 16 + l16][quad * 8];
            const bf16x8 pb1 = *(const bf16x8*)&ps[w * 16 + l16][32 + quad * 8];
            #pragma unroll
            for (int nt = 0; nt < 4; ++nt) {
                Os[nt] = MFMA16(*(const bf16x8*)&vt[cur][nt * 16 + l16][quad * 8], pb0, Os[nt]);
                Os[nt] = MFMA16(*(const bf16x8*)&vt[cur][nt * 16 + l16][32 + quad * 8], pb1, Os[nt]);
            }
        }

        // ---- relative-position term ----
        if (dorel) {
            #pragma unroll
            for (int st = 0; st < 5; ++st) {
                f32x4 acc = zero4;
                acc = MFMA16(e0[st], qa0, acc);
                acc = MFMA16(e1[st], qa1, acc);
                // skew scatter: k-col = st*16+quad*4+r+l16-15, mask t>1023
                #pragma unroll
                for (int r = 0; r < 4; ++r) {
                    const int kc = st * 16 + quad * 4 + r + l16 - 15;
                    const int tg = tb + st * 16 + quad * 4 + r;
                    if (kc >= 0 && kc < 64)
                        ps[w * 16 + l16][kc] = (tg <= 1023) ? (__bf16)acc[r]
                                                            : (__bf16)0.0f;
                }
            }
            const bf16x8 rb0 = *(const bf16x8*)&ps[w * 16 + l16][quad * 8];
            const bf16x8 rb1 = *(const bf16x8*)&ps[w * 16 + l16][32 + quad * 8];
            #pragma unroll
            for (int nt = 0; nt < 4; ++nt) {
                Or[nt] = MFMA16(*(const bf16x8*)&vt[cur][nt * 16 + l16][quad * 8], rb0, Or[nt]);
                Or[nt] = MFMA16(*(const bf16x8*)&vt[cur][nt * 16 + l16][32 + quad * 8], rb1, Or[nt]);
            }
        }
        __syncthreads();
    }

    // ---- epilogue: one cross-lane lsum reduce, assemble in ps, b128 stores --
    esum += __shfl_xor(esum, 16, 64);
    esum += __shfl_xor(esum, 32, 64);
    const float invl = 1.0f / esum;
    #pragma unroll
    for (int nt = 0; nt < 4; ++nt) {
        bf16x4 ov;
        #pragma unroll
        for (int r = 0; r < 4; ++r)
            ov[r] = (__bf16)(Os[nt][r] * invl + Or[nt][r]);
        *(bf16x4*)&ps[w * 16 + l16][nt * 16 + quad * 4] = ov;
    }
    const int erow = lane >> 3, ec8 = lane & 7;
    #pragma unroll
    for (int i = 0; i < 2; ++i) {
        const int r = erow + i * 8;
        const float4 val = *(const float4*)&ps[w * 16 + r][ec8 * 8];
        *(float4*)(attnA + ((size_t)(n * L_ + qw0 + r)) * E_ + h * 64 + ec8 * 8) = val;
    }
}

// ---------------------------------------------------------------------------
// proj: out (8192 x 1024) f32 = attnA (bf16) @ Wo^T (bf16) + bo.
// 128x128 C tile, BK=64, global_load_lds width-16 staging.
// ---------------------------------------------------------------------------
__global__ __launch_bounds__(256) void proj_kernel(
    const __bf16* __restrict__ A, const __bf16* __restrict__ W,
    const float* __restrict__ bo, float* __restrict__ out)
{
    const int bid = blockIdx.x;
    const int rt = bid >> 3, ct = bid & 7;
    const int r0 = rt * 128, c0 = ct * 128;
    const int t = threadIdx.x, w = t >> 6, lane = t & 63;
    const int quad = lane >> 4, l16 = lane & 15;
    const int wm = w >> 1, wn = w & 1;

    __shared__ __bf16 As[128 * 64];
    __shared__ __bf16 Bs[128 * 64];

    f32x4 acc[16];
    const f32x4 zero4 = {0.f, 0.f, 0.f, 0.f};
    #pragma unroll
    for (int i = 0; i < 16; ++i) acc[i] = zero4;

    const int lrow = lane >> 3, lcg = lane & 7;

    for (int kt = 0; kt < 16; ++kt) {
        const int e0 = kt * 64;
        __syncthreads();
        #pragma unroll
        for (int i = 0; i < 4; ++i) {
            const int chunk = w * 4 + i;
            const int row = chunk * 8 + lrow;
            const __bf16* ga = A + (size_t)(r0 + row) * E_ + e0 + lcg * 8;
            const __bf16* gb = W + (size_t)(c0 + row) * E_ + e0 + lcg * 8;
            __builtin_amdgcn_global_load_lds(
                (const __attribute__((address_space(1))) void*)ga,
                (__attribute__((address_space(3))) void*)&As[chunk * 512], 16, 0, 0);
            __builtin_amdgcn_global_load_lds(
                (const __attribute__((address_space(1))) void*)gb,
                (__attribute__((address_space(3))) void*)&Bs[chunk * 512], 16, 0, 0);
        }
        __syncthreads();
        #pragma unroll
        for (int c = 0; c < 2; ++c) {
            bf16x8 am[4], bn[4];
            #pragma unroll
            for (int i = 0; i < 4; ++i) {
                am[i] = *(const bf16x8*)&As[(wm * 64 + i * 16 + l16) * 64 + c * 32 + quad * 8];
                bn[i] = *(const bf16x8*)&Bs[(wn * 64 + i * 16 + l16) * 64 + c * 32 + quad * 8];
            }
            #pragma unroll
            for (int i = 0; i < 4; ++i)
                #pragma unroll
                for (int j = 0; j < 4; ++j)
                    acc[i * 4 + j] = MFMA16(am[i], bn[j], acc[i * 4 + j]);
        }
    }

    #pragma unroll
    for (int i = 0; i < 4; ++i)
        #pragma unroll
        for (int j = 0; j < 4; ++j) {
            const int col = c0 + wn * 64 + j * 16 + l16;
            const float bb = bo[col];
            #pragma unroll
            for (int r = 0; r < 4; ++r)
                out[(size_t)(r0 + wm * 64 + i * 16 + quad * 4 + r) * E_ + col] =
                    acc[i * 4 + j][r] + bb;
        }
}

// ---------------------------------------------------------------------------
extern "C" void kernel_launch(void* const* d_in, const int* in_sizes, int n_in,
                              void* d_out, int out_size, void* d_ws, size_t ws_size,
                              hipStream_t stream)
{
    const float* x    = (const float*)d_in[0];
    const float* Wq   = (const float*)d_in[1];
    const float* bq   = (const float*)d_in[2];
    const float* Wk   = (const float*)d_in[3];
    const float* bk   = (const float*)d_in[4];
    const float* Wv   = (const float*)d_in[5];
    const float* bv   = (const float*)d_in[6];
    const float* Erel = (const float*)d_in[7];
    const float* Wo   = (const float*)d_in[8];
    const float* bo   = (const float*)d_in[9];
    float* out = (float*)d_out;

    char* p = (char*)d_ws;
    __bf16* qbf   = (__bf16*)p; p += (size_t)N_ * L_ * H_ * D_ * 2;  // 16 MB
    __bf16* kbf   = (__bf16*)p; p += (size_t)N_ * L_ * H_ * D_ * 2;  // scaled K
    __bf16* vbf   = (__bf16*)p; p += (size_t)N_ * L_ * H_ * D_ * 2;
    __bf16* vtrb  = (__bf16*)p; p += (size_t)N_ * L_ * H_ * D_ * 2;  // V^T
    __bf16* attnA = (__bf16*)p; p += (size_t)N_ * L_ * E_ * 2;       // 16 MB
    __bf16* wobf  = (__bf16*)p; p += (size_t)E_ * E_ * 2;            // 2 MB
    __bf16* erbf  = (__bf16*)p; p += (size_t)L_ * D_ * 2;            // 128 KB

    prep_kernel<<<1088, 256, 0, stream>>>(Wo, Erel, wobf, erbf);
    qkv_kernel<<<(N_ * L_ * H_) / 64, 256, 0, stream>>>(x, Wq, bq, Wk, bk, Wv, bv,
                                                        qbf, kbf, vbf);
    vtr_kernel<<<N_ * H_ * (L_ / 64), 256, 0, stream>>>(vbf, vtrb);
    attn_kernel<<<N_ * H_ * (L_ / 128), 512, 0, stream>>>(qbf, kbf, vtrb, erbf, attnA);
    proj_kernel<<<(N_ * L_ / 128) * (E_ / 128), 256, 0, stream>>>(attnA, wobf, bo, out);
}

// Round 6
// 312.153 us; speedup vs baseline: 1.5179x; 1.5179x over previous
//
#include <hip/hip_runtime.h>
#include <math.h>

#define N_ 8
#define L_ 1024
#define H_ 16
#define E_ 1024
#define D_ 64

typedef __bf16 bf16x8 __attribute__((ext_vector_type(8)));
typedef __bf16 bf16x4 __attribute__((ext_vector_type(4)));
typedef float  f32x4  __attribute__((ext_vector_type(4)));

#define MFMA16(a, b, c) __builtin_amdgcn_mfma_f32_16x16x32_bf16((a), (b), (c), 0, 0, 0)

// exp(s/32) == exp2(s * KSCALE) with KSCALE folded into K at projection time.
#define KSCALE 0.04508422002778011f   // log2(e)/32

// ---------------------------------------------------------------------------
// prep: convert Wo (1M) and Erel (64K) f32 -> bf16 scratch.
// ---------------------------------------------------------------------------
__global__ __launch_bounds__(256) void prep_kernel(
    const float* __restrict__ Wo, const float* __restrict__ Erel,
    __bf16* __restrict__ wobf, __bf16* __restrict__ erbf)
{
    const int idx = blockIdx.x * 256 + threadIdx.x;
    const float* src;
    __bf16* dst;
    int off;
    if (blockIdx.x < 1024) { src = Wo;   dst = wobf; off = idx * 4; }
    else                   { src = Erel; dst = erbf; off = (idx - 1024 * 256) * 4; }
    const float4 f = *(const float4*)(src + off);
    bf16x4 h;
    h[0] = (__bf16)f.x; h[1] = (__bf16)f.y; h[2] = (__bf16)f.z; h[3] = (__bf16)f.w;
    *(bf16x4*)(dst + off) = h;
}

// ---------------------------------------------------------------------------
// qkv: x viewed as (131072 x 64) row-major (rows m=(n,l,h)); q/k/v = x @ W^T + b
// K is pre-scaled by KSCALE (softmax base-2 fold). Epilogue goes through an
// LDS transpose so global stores are coalesced b128.
// ---------------------------------------------------------------------------
__global__ __launch_bounds__(256) void qkv_kernel(
    const float* __restrict__ x,
    const float* __restrict__ Wq, const float* __restrict__ bq,
    const float* __restrict__ Wk, const float* __restrict__ bk,
    const float* __restrict__ Wv, const float* __restrict__ bv,
    __bf16* __restrict__ qo, __bf16* __restrict__ ko, __bf16* __restrict__ vo)
{
    const int t = threadIdx.x, w = t >> 6, lane = t & 63;
    const int quad = lane >> 4, l16 = lane & 15;
    const int m0 = blockIdx.x * 64;

    __shared__ __bf16 xs[64][72];
    __shared__ __bf16 wls[3][64][72];

    #pragma unroll
    for (int i = 0; i < 4; ++i) {
        const int idx = t + i * 256, row = idx >> 4, c4 = idx & 15;
        {
            const float4 f = *(const float4*)(x + (size_t)(m0 + row) * 64 + c4 * 4);
            bf16x4 hh; hh[0]=(__bf16)f.x; hh[1]=(__bf16)f.y; hh[2]=(__bf16)f.z; hh[3]=(__bf16)f.w;
            *(bf16x4*)&xs[row][c4 * 4] = hh;
        }
        {
            const float4 f = *(const float4*)(Wq + (size_t)row * 64 + c4 * 4);
            bf16x4 hh; hh[0]=(__bf16)f.x; hh[1]=(__bf16)f.y; hh[2]=(__bf16)f.z; hh[3]=(__bf16)f.w;
            *(bf16x4*)&wls[0][row][c4 * 4] = hh;
        }
        {
            const float4 f = *(const float4*)(Wk + (size_t)row * 64 + c4 * 4);
            bf16x4 hh; hh[0]=(__bf16)f.x; hh[1]=(__bf16)f.y; hh[2]=(__bf16)f.z; hh[3]=(__bf16)f.w;
            *(bf16x4*)&wls[1][row][c4 * 4] = hh;
        }
        {
            const float4 f = *(const float4*)(Wv + (size_t)row * 64 + c4 * 4);
            bf16x4 hh; hh[0]=(__bf16)f.x; hh[1]=(__bf16)f.y; hh[2]=(__bf16)f.z; hh[3]=(__bf16)f.w;
            *(bf16x4*)&wls[2][row][c4 * 4] = hh;
        }
    }
    __syncthreads();

    bf16x8 a[2];
    a[0] = *(const bf16x8*)&xs[w * 16 + l16][quad * 8];
    a[1] = *(const bf16x8*)&xs[w * 16 + l16][32 + quad * 8];

    f32x4 acc[12];
    const f32x4 zero4 = {0.f, 0.f, 0.f, 0.f};
    #pragma unroll
    for (int nt = 0; nt < 12; ++nt) acc[nt] = zero4;

    #pragma unroll
    for (int nt = 0; nt < 12; ++nt) {
        const int sel = nt >> 2, dt = nt & 3;
        #pragma unroll
        for (int c = 0; c < 2; ++c) {
            const bf16x8 b = *(const bf16x8*)&wls[sel][dt * 16 + l16][c * 32 + quad * 8];
            acc[nt] = MFMA16(a[c], b, acc[nt]);
        }
    }
    __syncthreads();   // wls reads done -> reuse as transpose staging

    // epilogue: C-frags -> ts[64][208] (cols: sel*64 + d), then coalesced dump
    __bf16* ts = &wls[0][0][0];
    const float* bias[3] = {bq, bk, bv};
    __bf16* outp[3] = {qo, ko, vo};
    #pragma unroll
    for (int nt = 0; nt < 12; ++nt) {
        const int sel = nt >> 2, dt = nt & 3;
        const float bb = bias[sel][dt * 16 + l16];
        const float scl = (sel == 1) ? KSCALE : 1.0f;
        #pragma unroll
        for (int r = 0; r < 4; ++r)
            ts[(size_t)(w * 16 + quad * 4 + r) * 208 + sel * 64 + dt * 16 + l16] =
                (__bf16)((acc[nt][r] + bb) * scl);
    }
    __syncthreads();
    #pragma unroll
    for (int sel = 0; sel < 3; ++sel)
        #pragma unroll
        for (int i = 0; i < 2; ++i) {
            const int idx = t * 2 + i, row = idx >> 3, c = idx & 7;
            *(float4*)(outp[sel] + (size_t)(m0 + row) * 64 + c * 8) =
                *(const float4*)&ts[(size_t)row * 208 + sel * 64 + c * 8];
        }
}

// ---------------------------------------------------------------------------
// vtr: v (n,l,h,d) -> vtr (n,h,d,l)  [64x64 tiles through LDS]
// ---------------------------------------------------------------------------
__global__ __launch_bounds__(256) void vtr_kernel(
    const __bf16* __restrict__ v, __bf16* __restrict__ vt)
{
    const int bid = blockIdx.x;
    const int lt = bid & 15, h = (bid >> 4) & 15, n = bid >> 8;
    const int l0 = lt * 64;
    const int t = threadIdx.x;
    __shared__ __bf16 ls[64][72];    // [d][l]

    const int lrow = t & 63, c0 = t >> 6;
    #pragma unroll
    for (int i = 0; i < 2; ++i) {
        const int c = c0 + i * 4;
        union { float4 f; __bf16 hv[8]; } u;
        u.f = *(const float4*)(v + ((size_t)(n * L_ + l0 + lrow) * H_ + h) * D_ + c * 8);
        #pragma unroll
        for (int j = 0; j < 8; ++j) ls[c * 8 + j][lrow] = u.hv[j];
    }
    __syncthreads();
    const int drow0 = t >> 3, lc = t & 7;
    #pragma unroll
    for (int i = 0; i < 2; ++i) {
        const int d = drow0 + i * 32;
        *(float4*)(vt + ((size_t)(n * H_ + h) * D_ + d) * L_ + l0 + lc * 8) =
            *(const float4*)&ls[d][lc * 8];
    }
}

// ---------------------------------------------------------------------------
// attn: 512 threads (8 waves), 128 q rows per block, computed transposed
// (lane's l16 = q). Fixed-base softmax: K pre-scaled by log2(e)/32, so
// P = exp2(S') with NO running max / rescale; per-lane esum deferred to one
// epilogue reduce. Double-buffered K/V; V pre-transposed (b128 staging both
// ways). Erel frags read at their MFMA use site -- NO prefetch arrays
// (round-5's e0[5]/e1[5] caused VGPR spill -> 512 MB scratch writebacks).
// ---------------------------------------------------------------------------
__global__ __launch_bounds__(512, 4) void attn_kernel(
    const __bf16* __restrict__ qbf, const __bf16* __restrict__ kbf,
    const __bf16* __restrict__ vtrb, const __bf16* __restrict__ erbf,
    __bf16* __restrict__ attnA)
{
    const int bid = blockIdx.x;
    // XCD swizzle: all 8 q-tiles of one (n,h) share bid%8 -> same XCD L2.
    const int p  = (bid & 7) | ((bid >> 6) << 3);
    const int qt = (bid >> 3) & 7;
    const int h = p & 15, n = p >> 4;
    const int q0 = qt * 128;
    const int t = threadIdx.x, w = t >> 6, lane = t & 63;
    const int quad = lane >> 4, l16 = lane & 15;

    __shared__ __bf16 ks[2][64][72];  // K tile row-major (key, d)
    __shared__ __bf16 vt[2][64][72];  // V^T tile (d, key)
    __shared__ __bf16 ps[128][72];    // exp-P / rel / epilogue (wave-private rows)

    const int qw0 = q0 + w * 16;
    const size_t qrowoff = ((size_t)(n * L_ + qw0 + l16) * H_ + h) * D_;
    const bf16x8 qa0 = *(const bf16x8*)(qbf + qrowoff + quad * 8);
    const bf16x8 qa1 = *(const bf16x8*)(qbf + qrowoff + 32 + quad * 8);

    const __bf16* kbase = kbf + ((size_t)n * L_ * H_ + h) * D_;        // rows l
    const __bf16* vbase = vtrb + ((size_t)(n * H_ + h) * D_) * L_;     // rows d
    const int srow = t >> 3, sc8 = (t & 7) * 8;   // one float4 per thread

    // tile 0 -> buf 0; tile 1 -> regs
    float4 kreg = *(const float4*)(kbase + (size_t)srow * 1024 + sc8);
    float4 vreg = *(const float4*)(vbase + (size_t)srow * 1024 + sc8);
    *(float4*)&ks[0][srow][sc8] = kreg;
    *(float4*)&vt[0][srow][sc8] = vreg;
    kreg = *(const float4*)(kbase + 64 * 1024 + (size_t)srow * 1024 + sc8);
    vreg = *(const float4*)(vbase + 64 + (size_t)srow * 1024 + sc8);
    __syncthreads();

    const f32x4 zero4 = {0.f, 0.f, 0.f, 0.f};
    f32x4 Os[4], Or[4];
    #pragma unroll
    for (int nt = 0; nt < 4; ++nt) { Os[nt] = zero4; Or[nt] = zero4; }
    float esum = 0.f;

    for (int kt = 0; kt < 16; ++kt) {
        const int cur = kt & 1;
        if (kt < 15) {
            *(float4*)&ks[cur ^ 1][srow][sc8] = kreg;
            *(float4*)&vt[cur ^ 1][srow][sc8] = vreg;
            if (kt < 14) {
                kreg = *(const float4*)(kbase + (size_t)(kt + 2) * 64 * 1024
                                        + (size_t)srow * 1024 + sc8);
                vreg = *(const float4*)(vbase + (kt + 2) * 64
                                        + (size_t)srow * 1024 + sc8);
            }
        }

        // ---- S'^T = K' Q^T (K pre-scaled by log2e/32) ----
        f32x4 sc[4];
        #pragma unroll
        for (int nt = 0; nt < 4; ++nt) {
            f32x4 acc = zero4;
            acc = MFMA16(*(const bf16x8*)&ks[cur][nt * 16 + l16][quad * 8], qa0, acc);
            acc = MFMA16(*(const bf16x8*)&ks[cur][nt * 16 + l16][32 + quad * 8], qa1, acc);
            sc[nt] = acc;
        }

        // ---- fixed-base exp + deferred lsum; pack exp-P to ps ----
        #pragma unroll
        for (int nt = 0; nt < 4; ++nt) {
            bf16x4 pk;
            #pragma unroll
            for (int r = 0; r < 4; ++r) {
                const float e = exp2f(sc[nt][r]);
                esum += e;
                pk[r] = (__bf16)e;
            }
            *(bf16x4*)&ps[w * 16 + l16][nt * 16 + quad * 4] = pk;
        }

        // ---- out^T += V^T P^T ----
        {
            const bf16x8 pb0 = *(const bf16x8*)&ps[w * 16 + l16][quad * 8];
            const bf16x8 pb1 = *(const bf16x8*)&ps[w * 16 + l16][32 + quad * 8];
            #pragma unroll
            for (int nt = 0; nt < 4; ++nt) {
                Os[nt] = MFMA16(*(const bf16x8*)&vt[cur][nt * 16 + l16][quad * 8], pb0, Os[nt]);
                Os[nt] = MFMA16(*(const bf16x8*)&vt[cur][nt * 16 + l16][32 + quad * 8], pb1, Os[nt]);
            }
        }

        // ---- relative-position term (Erel read at use site; no arrays) ----
        if (kt * 64 <= qw0 + 15) {
            const int tb = kt * 64 + 1008 - qw0;   // >= 0 always
            #pragma unroll
            for (int st = 0; st < 5; ++st) {
                int tr = tb + st * 16 + l16;
                tr = tr > 1023 ? 1023 : tr;        // clamped rows masked below
                const __bf16* er = erbf + (size_t)tr * 64;
                f32x4 acc = zero4;
                acc = MFMA16(*(const bf16x8*)(er + quad * 8), qa0, acc);
                acc = MFMA16(*(const bf16x8*)(er + 32 + quad * 8), qa1, acc);
                // skew scatter: k-col = st*16+quad*4+r+l16-15, mask t>1023
                #pragma unroll
                for (int r = 0; r < 4; ++r) {
                    const int kc = st * 16 + quad * 4 + r + l16 - 15;
                    const int tg = tb + st * 16 + quad * 4 + r;
                    if (kc >= 0 && kc < 64)
                        ps[w * 16 + l16][kc] = (tg <= 1023) ? (__bf16)acc[r]
                                                            : (__bf16)0.0f;
                }
            }
            const bf16x8 rb0 = *(const bf16x8*)&ps[w * 16 + l16][quad * 8];
            const bf16x8 rb1 = *(const bf16x8*)&ps[w * 16 + l16][32 + quad * 8];
            #pragma unroll
            for (int nt = 0; nt < 4; ++nt) {
                Or[nt] = MFMA16(*(const bf16x8*)&vt[cur][nt * 16 + l16][quad * 8], rb0, Or[nt]);
                Or[nt] = MFMA16(*(const bf16x8*)&vt[cur][nt * 16 + l16][32 + quad * 8], rb1, Or[nt]);
            }
        }
        __syncthreads();
    }

    // ---- epilogue: one cross-lane lsum reduce, assemble in ps, b128 stores --
    esum += __shfl_xor(esum, 16, 64);
    esum += __shfl_xor(esum, 32, 64);
    const float invl = 1.0f / esum;
    #pragma unroll
    for (int nt = 0; nt < 4; ++nt) {
        bf16x4 ov;
        #pragma unroll
        for (int r = 0; r < 4; ++r)
            ov[r] = (__bf16)(Os[nt][r] * invl + Or[nt][r]);
        *(bf16x4*)&ps[w * 16 + l16][nt * 16 + quad * 4] = ov;
    }
    const int erow = lane >> 3, ec8 = lane & 7;
    #pragma unroll
    for (int i = 0; i < 2; ++i) {
        const int r = erow + i * 8;
        const float4 val = *(const float4*)&ps[w * 16 + r][ec8 * 8];
        *(float4*)(attnA + ((size_t)(n * L_ + qw0 + r)) * E_ + h * 64 + ec8 * 8) = val;
    }
}

// ---------------------------------------------------------------------------
// proj: out (8192 x 1024) f32 = attnA (bf16) @ Wo^T (bf16) + bo.
// 128x128 C tile, BK=64, global_load_lds width-16 staging.
// ---------------------------------------------------------------------------
__global__ __launch_bounds__(256) void proj_kernel(
    const __bf16* __restrict__ A, const __bf16* __restrict__ W,
    const float* __restrict__ bo, float* __restrict__ out)
{
    const int bid = blockIdx.x;
    const int rt = bid >> 3, ct = bid & 7;
    const int r0 = rt * 128, c0 = ct * 128;
    const int t = threadIdx.x, w = t >> 6, lane = t & 63;
    const int quad = lane >> 4, l16 = lane & 15;
    const int wm = w >> 1, wn = w & 1;

    __shared__ __bf16 As[128 * 64];
    __shared__ __bf16 Bs[128 * 64];

    f32x4 acc[16];
    const f32x4 zero4 = {0.f, 0.f, 0.f, 0.f};
    #pragma unroll
    for (int i = 0; i < 16; ++i) acc[i] = zero4;

    const int lrow = lane >> 3, lcg = lane & 7;

    for (int kt = 0; kt < 16; ++kt) {
        const int e0 = kt * 64;
        __syncthreads();
        #pragma unroll
        for (int i = 0; i < 4; ++i) {
            const int chunk = w * 4 + i;
            const int row = chunk * 8 + lrow;
            const __bf16* ga = A + (size_t)(r0 + row) * E_ + e0 + lcg * 8;
            const __bf16* gb = W + (size_t)(c0 + row) * E_ + e0 + lcg * 8;
            __builtin_amdgcn_global_load_lds(
                (const __attribute__((address_space(1))) void*)ga,
                (__attribute__((address_space(3))) void*)&As[chunk * 512], 16, 0, 0);
            __builtin_amdgcn_global_load_lds(
                (const __attribute__((address_space(1))) void*)gb,
                (__attribute__((address_space(3))) void*)&Bs[chunk * 512], 16, 0, 0);
        }
        __syncthreads();
        #pragma unroll
        for (int c = 0; c < 2; ++c) {
            bf16x8 am[4], bn[4];
            #pragma unroll
            for (int i = 0; i < 4; ++i) {
                am[i] = *(const bf16x8*)&As[(wm * 64 + i * 16 + l16) * 64 + c * 32 + quad * 8];
                bn[i] = *(const bf16x8*)&Bs[(wn * 64 + i * 16 + l16) * 64 + c * 32 + quad * 8];
            }
            #pragma unroll
            for (int i = 0; i < 4; ++i)
                #pragma unroll
                for (int j = 0; j < 4; ++j)
                    acc[i * 4 + j] = MFMA16(am[i], bn[j], acc[i * 4 + j]);
        }
    }

    #pragma unroll
    for (int i = 0; i < 4; ++i)
        #pragma unroll
        for (int j = 0; j < 4; ++j) {
            const int col = c0 + wn * 64 + j * 16 + l16;
            const float bb = bo[col];
            #pragma unroll
            for (int r = 0; r < 4; ++r)
                out[(size_t)(r0 + wm * 64 + i * 16 + quad * 4 + r) * E_ + col] =
                    acc[i * 4 + j][r] + bb;
        }
}

// ---------------------------------------------------------------------------
extern "C" void kernel_launch(void* const* d_in, const int* in_sizes, int n_in,
                              void* d_out, int out_size, void* d_ws, size_t ws_size,
                              hipStream_t stream)
{
    const float* x    = (const float*)d_in[0];
    const float* Wq   = (const float*)d_in[1];
    const float* bq   = (const float*)d_in[2];
    const float* Wk   = (const float*)d_in[3];
    const float* bk   = (const float*)d_in[4];
    const float* Wv   = (const float*)d_in[5];
    const float* bv   = (const float*)d_in[6];
    const float* Erel = (const float*)d_in[7];
    const float* Wo   = (const float*)d_in[8];
    const float* bo   = (const float*)d_in[9];
    float* out = (float*)d_out;

    char* p = (char*)d_ws;
    __bf16* qbf   = (__bf16*)p; p += (size_t)N_ * L_ * H_ * D_ * 2;  // 16 MB
    __bf16* kbf   = (__bf16*)p; p += (size_t)N_ * L_ * H_ * D_ * 2;  // scaled K
    __bf16* vbf   = (__bf16*)p; p += (size_t)N_ * L_ * H_ * D_ * 2;
    __bf16* vtrb  = (__bf16*)p; p += (size_t)N_ * L_ * H_ * D_ * 2;  // V^T
    __bf16* attnA = (__bf16*)p; p += (size_t)N_ * L_ * E_ * 2;       // 16 MB
    __bf16* wobf  = (__bf16*)p; p += (size_t)E_ * E_ * 2;            // 2 MB
    __bf16* erbf  = (__bf16*)p; p += (size_t)L_ * D_ * 2;            // 128 KB

    prep_kernel<<<1088, 256, 0, stream>>>(Wo, Erel, wobf, erbf);
    qkv_kernel<<<(N_ * L_ * H_) / 64, 256, 0, stream>>>(x, Wq, bq, Wk, bk, Wv, bv,
                                                        qbf, kbf, vbf);
    vtr_kernel<<<N_ * H_ * (L_ / 64), 256, 0, stream>>>(vbf, vtrb);
    attn_kernel<<<N_ * H_ * (L_ / 128), 512, 0, stream>>>(qbf, kbf, vtrb, erbf, attnA);
    proj_kernel<<<(N_ * L_ / 128) * (E_ / 128), 256, 0, stream>>>(attnA, wobf, bo, out);
}

// Round 8
// 303.543 us; speedup vs baseline: 1.5610x; 1.0284x over previous
//
#include <hip/hip_runtime.h>
#include <math.h>

#define N_ 8
#define L_ 1024
#define H_ 16
#define E_ 1024
#define D_ 64

typedef __bf16 bf16x8 __attribute__((ext_vector_type(8)));
typedef __bf16 bf16x4 __attribute__((ext_vector_type(4)));
typedef float  f32x4  __attribute__((ext_vector_type(4)));

#define MFMA16(a, b, c) __builtin_amdgcn_mfma_f32_16x16x32_bf16((a), (b), (c), 0, 0, 0)

// exp(s/32) == exp2(s * KSCALE) with KSCALE folded into K at projection time.
#define KSCALE 0.04508422002778011f   // log2(e)/32

// ---------------------------------------------------------------------------
// prep: convert Wo (1M) and Erel (64K) f32 -> bf16 scratch.
// ---------------------------------------------------------------------------
__global__ __launch_bounds__(256) void prep_kernel(
    const float* __restrict__ Wo, const float* __restrict__ Erel,
    __bf16* __restrict__ wobf, __bf16* __restrict__ erbf)
{
    const int idx = blockIdx.x * 256 + threadIdx.x;
    const float* src;
    __bf16* dst;
    int off;
    if (blockIdx.x < 1024) { src = Wo;   dst = wobf; off = idx * 4; }
    else                   { src = Erel; dst = erbf; off = (idx - 1024 * 256) * 4; }
    const float4 f = *(const float4*)(src + off);
    bf16x4 h;
    h[0] = (__bf16)f.x; h[1] = (__bf16)f.y; h[2] = (__bf16)f.z; h[3] = (__bf16)f.w;
    *(bf16x4*)(dst + off) = h;
}

// ---------------------------------------------------------------------------
// qkv: x viewed as (131072 x 64) row-major (rows m=(n,l,h)); q/k/v = x @ W^T + b
// K pre-scaled by KSCALE. Epilogue via LDS transpose -> coalesced b128 stores.
// ---------------------------------------------------------------------------
__global__ __launch_bounds__(256) void qkv_kernel(
    const float* __restrict__ x,
    const float* __restrict__ Wq, const float* __restrict__ bq,
    const float* __restrict__ Wk, const float* __restrict__ bk,
    const float* __restrict__ Wv, const float* __restrict__ bv,
    __bf16* __restrict__ qo, __bf16* __restrict__ ko, __bf16* __restrict__ vo)
{
    const int t = threadIdx.x, w = t >> 6, lane = t & 63;
    const int quad = lane >> 4, l16 = lane & 15;
    const int m0 = blockIdx.x * 64;

    __shared__ __bf16 xs[64][72];
    __shared__ __bf16 wls[3][64][72];

    #pragma unroll
    for (int i = 0; i < 4; ++i) {
        const int idx = t + i * 256, row = idx >> 4, c4 = idx & 15;
        {
            const float4 f = *(const float4*)(x + (size_t)(m0 + row) * 64 + c4 * 4);
            bf16x4 hh; hh[0]=(__bf16)f.x; hh[1]=(__bf16)f.y; hh[2]=(__bf16)f.z; hh[3]=(__bf16)f.w;
            *(bf16x4*)&xs[row][c4 * 4] = hh;
        }
        {
            const float4 f = *(const float4*)(Wq + (size_t)row * 64 + c4 * 4);
            bf16x4 hh; hh[0]=(__bf16)f.x; hh[1]=(__bf16)f.y; hh[2]=(__bf16)f.z; hh[3]=(__bf16)f.w;
            *(bf16x4*)&wls[0][row][c4 * 4] = hh;
        }
        {
            const float4 f = *(const float4*)(Wk + (size_t)row * 64 + c4 * 4);
            bf16x4 hh; hh[0]=(__bf16)f.x; hh[1]=(__bf16)f.y; hh[2]=(__bf16)f.z; hh[3]=(__bf16)f.w;
            *(bf16x4*)&wls[1][row][c4 * 4] = hh;
        }
        {
            const float4 f = *(const float4*)(Wv + (size_t)row * 64 + c4 * 4);
            bf16x4 hh; hh[0]=(__bf16)f.x; hh[1]=(__bf16)f.y; hh[2]=(__bf16)f.z; hh[3]=(__bf16)f.w;
            *(bf16x4*)&wls[2][row][c4 * 4] = hh;
        }
    }
    __syncthreads();

    bf16x8 a[2];
    a[0] = *(const bf16x8*)&xs[w * 16 + l16][quad * 8];
    a[1] = *(const bf16x8*)&xs[w * 16 + l16][32 + quad * 8];

    f32x4 acc[12];
    const f32x4 zero4 = {0.f, 0.f, 0.f, 0.f};
    #pragma unroll
    for (int nt = 0; nt < 12; ++nt) acc[nt] = zero4;

    #pragma unroll
    for (int nt = 0; nt < 12; ++nt) {
        const int sel = nt >> 2, dt = nt & 3;
        #pragma unroll
        for (int c = 0; c < 2; ++c) {
            const bf16x8 b = *(const bf16x8*)&wls[sel][dt * 16 + l16][c * 32 + quad * 8];
            acc[nt] = MFMA16(a[c], b, acc[nt]);
        }
    }
    __syncthreads();   // wls reads done -> reuse as transpose staging

    __bf16* ts = &wls[0][0][0];
    const float* bias[3] = {bq, bk, bv};
    __bf16* outp[3] = {qo, ko, vo};
    #pragma unroll
    for (int nt = 0; nt < 12; ++nt) {
        const int sel = nt >> 2, dt = nt & 3;
        const float bb = bias[sel][dt * 16 + l16];
        const float scl = (sel == 1) ? KSCALE : 1.0f;
        #pragma unroll
        for (int r = 0; r < 4; ++r)
            ts[(size_t)(w * 16 + quad * 4 + r) * 208 + sel * 64 + dt * 16 + l16] =
                (__bf16)((acc[nt][r] + bb) * scl);
    }
    __syncthreads();
    #pragma unroll
    for (int sel = 0; sel < 3; ++sel)
        #pragma unroll
        for (int i = 0; i < 2; ++i) {
            const int idx = t * 2 + i, row = idx >> 3, c = idx & 7;
            *(float4*)(outp[sel] + (size_t)(m0 + row) * 64 + c * 8) =
                *(const float4*)&ts[(size_t)row * 208 + sel * 64 + c * 8];
        }
}

// ---------------------------------------------------------------------------
// vtr: v (n,l,h,d) -> vtr (n,h,d,l)  [64x64 tiles through LDS]
// ---------------------------------------------------------------------------
__global__ __launch_bounds__(256) void vtr_kernel(
    const __bf16* __restrict__ v, __bf16* __restrict__ vt)
{
    const int bid = blockIdx.x;
    const int lt = bid & 15, h = (bid >> 4) & 15, n = bid >> 8;
    const int l0 = lt * 64;
    const int t = threadIdx.x;
    __shared__ __bf16 ls[64][72];    // [d][l]

    const int lrow = t & 63, c0 = t >> 6;
    #pragma unroll
    for (int i = 0; i < 2; ++i) {
        const int c = c0 + i * 4;
        union { float4 f; __bf16 hv[8]; } u;
        u.f = *(const float4*)(v + ((size_t)(n * L_ + l0 + lrow) * H_ + h) * D_ + c * 8);
        #pragma unroll
        for (int j = 0; j < 8; ++j) ls[c * 8 + j][lrow] = u.hv[j];
    }
    __syncthreads();
    const int drow0 = t >> 3, lc = t & 7;
    #pragma unroll
    for (int i = 0; i < 2; ++i) {
        const int d = drow0 + i * 32;
        *(float4*)(vt + ((size_t)(n * H_ + h) * D_ + d) * L_ + l0 + lc * 8) =
            *(const float4*)&ls[d][lc * 8];
    }
}

// ---------------------------------------------------------------------------
// rel: R = skew(Q Erel^T) masked, rbuf = R @ V. 512 thr / 8 waves; each wave
// owns 32 q rows (2 sub-tiles 128 apart) sharing every V^T LDS frag read.
// Triangular kt loop; qt descending so long blocks dispatch first.
// ---------------------------------------------------------------------------
__global__ __launch_bounds__(512, 4) void rel_kernel(
    const __bf16* __restrict__ qbf, const __bf16* __restrict__ vtrb,
    const __bf16* __restrict__ erbf, __bf16* __restrict__ rbuf)
{
    const int bid = blockIdx.x;
    const int qt = 3 - (bid >> 7);          // descending length
    const int p = bid & 127;                // (n,h): bid%8 stable across qt
    const int h = p & 15, n = p >> 4;
    const int q0 = qt * 256;
    const int t = threadIdx.x, w = t >> 6, lane = t & 63;
    const int quad = lane >> 4, l16 = lane & 15;

    __shared__ __bf16 vt[2][64][72];   // V^T tile (d, key)
    __shared__ __bf16 rs[128][72];     // skewed rel tiles (wave-private rows)

    const int qA = q0 + w * 16;        // sub-tile A first q row; B = qA + 128
    const size_t qoffA = ((size_t)(n * L_ + qA + l16) * H_ + h) * D_;
    const size_t qoffB = qoffA + (size_t)128 * H_ * D_;
    const bf16x8 qaA0 = *(const bf16x8*)(qbf + qoffA + quad * 8);
    const bf16x8 qaA1 = *(const bf16x8*)(qbf + qoffA + 32 + quad * 8);
    const bf16x8 qaB0 = *(const bf16x8*)(qbf + qoffB + quad * 8);
    const bf16x8 qaB1 = *(const bf16x8*)(qbf + qoffB + 32 + quad * 8);

    const __bf16* vbase = vtrb + ((size_t)(n * H_ + h) * D_) * L_;  // rows d
    const int srow = t >> 3, sc8 = (t & 7) * 8;
    const int ktmax = qt * 4 + 4;

    float4 vreg = *(const float4*)(vbase + (size_t)srow * 1024 + sc8);
    *(float4*)&vt[0][srow][sc8] = vreg;
    vreg = *(const float4*)(vbase + 64 + (size_t)srow * 1024 + sc8);
    __syncthreads();

    const f32x4 zero4 = {0.f, 0.f, 0.f, 0.f};
    f32x4 OrA[4], OrB[4];
    #pragma unroll
    for (int nt = 0; nt < 4; ++nt) { OrA[nt] = zero4; OrB[nt] = zero4; }

    for (int kt = 0; kt < ktmax; ++kt) {
        const int cur = kt & 1;
        if (kt + 1 < ktmax) {
            *(float4*)&vt[cur ^ 1][srow][sc8] = vreg;
            if (kt + 2 < ktmax)
                vreg = *(const float4*)(vbase + (kt + 2) * 64
                                        + (size_t)srow * 1024 + sc8);
        }

        const bool dorelA = (kt * 64 <= qA + 15);
        const bool dorelB = (kt * 64 <= qA + 128 + 15);
        bf16x8 rbA0, rbA1, rbB0, rbB1;

        if (dorelA) {
            const int tb = kt * 64 + 1008 - qA;
            #pragma unroll
            for (int st = 0; st < 5; ++st) {
                int tr = tb + st * 16 + l16;
                tr = tr > 1023 ? 1023 : tr;
                const __bf16* er = erbf + (size_t)tr * 64;
                f32x4 acc = zero4;
                acc = MFMA16(*(const bf16x8*)(er + quad * 8), qaA0, acc);
                acc = MFMA16(*(const bf16x8*)(er + 32 + quad * 8), qaA1, acc);
                #pragma unroll
                for (int r = 0; r < 4; ++r) {
                    const int kc = st * 16 + quad * 4 + r + l16 - 15;
                    const int tg = tb + st * 16 + quad * 4 + r;
                    if (kc >= 0 && kc < 64)
                        rs[w * 16 + l16][kc] = (tg <= 1023) ? (__bf16)acc[r]
                                                            : (__bf16)0.0f;
                }
            }
            rbA0 = *(const bf16x8*)&rs[w * 16 + l16][quad * 8];
            rbA1 = *(const bf16x8*)&rs[w * 16 + l16][32 + quad * 8];
        }
        if (dorelB) {   // reuse the same rs rows (per-wave DS ordering)
            const int tb = kt * 64 + 1008 - (qA + 128);
            #pragma unroll
            for (int st = 0; st < 5; ++st) {
                int tr = tb + st * 16 + l16;
                tr = tr > 1023 ? 1023 : tr;
                const __bf16* er = erbf + (size_t)tr * 64;
                f32x4 acc = zero4;
                acc = MFMA16(*(const bf16x8*)(er + quad * 8), qaB0, acc);
                acc = MFMA16(*(const bf16x8*)(er + 32 + quad * 8), qaB1, acc);
                #pragma unroll
                for (int r = 0; r < 4; ++r) {
                    const int kc = st * 16 + quad * 4 + r + l16 - 15;
                    const int tg = tb + st * 16 + quad * 4 + r;
                    if (kc >= 0 && kc < 64)
                        rs[w * 16 + l16][kc] = (tg <= 1023) ? (__bf16)acc[r]
                                                            : (__bf16)0.0f;
                }
            }
            rbB0 = *(const bf16x8*)&rs[w * 16 + l16][quad * 8];
            rbB1 = *(const bf16x8*)&rs[w * 16 + l16][32 + quad * 8];
        }

        // PV: each V^T frag read once, used for both sub-tiles
        #pragma unroll
        for (int nt = 0; nt < 4; ++nt) {
            const bf16x8 va0 = *(const bf16x8*)&vt[cur][nt * 16 + l16][quad * 8];
            const bf16x8 va1 = *(const bf16x8*)&vt[cur][nt * 16 + l16][32 + quad * 8];
            if (dorelA) {
                OrA[nt] = MFMA16(va0, rbA0, OrA[nt]);
                OrA[nt] = MFMA16(va1, rbA1, OrA[nt]);
            }
            if (dorelB) {
                OrB[nt] = MFMA16(va0, rbB0, OrB[nt]);
                OrB[nt] = MFMA16(va1, rbB1, OrB[nt]);
            }
        }
        __syncthreads();
    }

    // epilogue: assemble in rs (wave-private), coalesced b128 stores.
    // Global row = qA + r (qA is the wave base; NO lane term -- r7 bug was -l16)
    const int erow = lane >> 3, ec8 = lane & 7;
    #pragma unroll
    for (int nt = 0; nt < 4; ++nt) {
        bf16x4 ov;
        #pragma unroll
        for (int r = 0; r < 4; ++r) ov[r] = (__bf16)OrA[nt][r];
        *(bf16x4*)&rs[w * 16 + l16][nt * 16 + quad * 4] = ov;
    }
    #pragma unroll
    for (int i = 0; i < 2; ++i) {
        const int r = erow + i * 8;
        *(float4*)(rbuf + ((size_t)(n * L_ + qA + r)) * E_ + h * 64 + ec8 * 8) =
            *(const float4*)&rs[w * 16 + r][ec8 * 8];
    }
    #pragma unroll
    for (int nt = 0; nt < 4; ++nt) {
        bf16x4 ov;
        #pragma unroll
        for (int r = 0; r < 4; ++r) ov[r] = (__bf16)OrB[nt][r];
        *(bf16x4*)&rs[w * 16 + l16][nt * 16 + quad * 4] = ov;
    }
    #pragma unroll
    for (int i = 0; i < 2; ++i) {
        const int r = erow + i * 8;
        *(float4*)(rbuf + ((size_t)(n * L_ + qA + 128 + r)) * E_ + h * 64 + ec8 * 8) =
            *(const float4*)&rs[w * 16 + r][ec8 * 8];
    }
}

// ---------------------------------------------------------------------------
// flash: softmax(QK^T/32)@V, transposed per-lane softmax. 512 thr / 8 waves;
// each wave owns 32 q rows (2 sub-tiles), sharing every K and V^T frag read.
// Fixed-base exp2 (K pre-scaled), deferred esum. Epilogue adds rbuf (rel term).
// ---------------------------------------------------------------------------
__global__ __launch_bounds__(512, 4) void flash_kernel(
    const __bf16* __restrict__ qbf, const __bf16* __restrict__ kbf,
    const __bf16* __restrict__ vtrb, const __bf16* __restrict__ rbuf,
    __bf16* __restrict__ attnA)
{
    const int bid = blockIdx.x;
    const int qt = bid >> 7;
    const int p = bid & 127;               // bid%8 stable across qt -> XCD reuse
    const int h = p & 15, n = p >> 4;
    const int q0 = qt * 256;
    const int t = threadIdx.x, w = t >> 6, lane = t & 63;
    const int quad = lane >> 4, l16 = lane & 15;

    __shared__ __bf16 ks[2][64][72];   // K tile (key, d)
    __shared__ __bf16 vt[2][64][72];   // V^T tile (d, key)
    __shared__ __bf16 ps[128][72];     // exp-P / epilogue (wave-private rows)

    const int qA = q0 + w * 16;
    const size_t qoffA = ((size_t)(n * L_ + qA + l16) * H_ + h) * D_;
    const size_t qoffB = qoffA + (size_t)128 * H_ * D_;
    const bf16x8 qaA0 = *(const bf16x8*)(qbf + qoffA + quad * 8);
    const bf16x8 qaA1 = *(const bf16x8*)(qbf + qoffA + 32 + quad * 8);
    const bf16x8 qaB0 = *(const bf16x8*)(qbf + qoffB + quad * 8);
    const bf16x8 qaB1 = *(const bf16x8*)(qbf + qoffB + 32 + quad * 8);

    const __bf16* kbase = kbf + ((size_t)n * L_ * H_ + h) * D_;
    const __bf16* vbase = vtrb + ((size_t)(n * H_ + h) * D_) * L_;
    const int srow = t >> 3, sc8 = (t & 7) * 8;

    float4 kreg = *(const float4*)(kbase + (size_t)srow * 1024 + sc8);
    float4 vreg = *(const float4*)(vbase + (size_t)srow * 1024 + sc8);
    *(float4*)&ks[0][srow][sc8] = kreg;
    *(float4*)&vt[0][srow][sc8] = vreg;
    kreg = *(const float4*)(kbase + 64 * 1024 + (size_t)srow * 1024 + sc8);
    vreg = *(const float4*)(vbase + 64 + (size_t)srow * 1024 + sc8);
    __syncthreads();

    const f32x4 zero4 = {0.f, 0.f, 0.f, 0.f};
    f32x4 OsA[4], OsB[4];
    #pragma unroll
    for (int nt = 0; nt < 4; ++nt) { OsA[nt] = zero4; OsB[nt] = zero4; }
    float esumA = 0.f, esumB = 0.f;

    for (int kt = 0; kt < 16; ++kt) {
        const int cur = kt & 1;
        if (kt < 15) {
            *(float4*)&ks[cur ^ 1][srow][sc8] = kreg;
            *(float4*)&vt[cur ^ 1][srow][sc8] = vreg;
            if (kt < 14) {
                kreg = *(const float4*)(kbase + (size_t)(kt + 2) * 64 * 1024
                                        + (size_t)srow * 1024 + sc8);
                vreg = *(const float4*)(vbase + (kt + 2) * 64
                                        + (size_t)srow * 1024 + sc8);
            }
        }

        // ---- S'^T for both sub-tiles, each K frag read once ----
        f32x4 sA[4], sB[4];
        #pragma unroll
        for (int nt = 0; nt < 4; ++nt) {
            const bf16x8 ka0 = *(const bf16x8*)&ks[cur][nt * 16 + l16][quad * 8];
            const bf16x8 ka1 = *(const bf16x8*)&ks[cur][nt * 16 + l16][32 + quad * 8];
            f32x4 a = zero4;
            a = MFMA16(ka0, qaA0, a);
            a = MFMA16(ka1, qaA1, a);
            sA[nt] = a;
            f32x4 b = zero4;
            b = MFMA16(ka0, qaB0, b);
            b = MFMA16(ka1, qaB1, b);
            sB[nt] = b;
        }

        // ---- exp-P A -> ps, read B-frags; then B reusing the same rows ----
        #pragma unroll
        for (int nt = 0; nt < 4; ++nt) {
            bf16x4 pk;
            #pragma unroll
            for (int r = 0; r < 4; ++r) {
                const float e = exp2f(sA[nt][r]);
                esumA += e;
                pk[r] = (__bf16)e;
            }
            *(bf16x4*)&ps[w * 16 + l16][nt * 16 + quad * 4] = pk;
        }
        const bf16x8 pbA0 = *(const bf16x8*)&ps[w * 16 + l16][quad * 8];
        const bf16x8 pbA1 = *(const bf16x8*)&ps[w * 16 + l16][32 + quad * 8];
        #pragma unroll
        for (int nt = 0; nt < 4; ++nt) {
            bf16x4 pk;
            #pragma unroll
            for (int r = 0; r < 4; ++r) {
                const float e = exp2f(sB[nt][r]);
                esumB += e;
                pk[r] = (__bf16)e;
            }
            *(bf16x4*)&ps[w * 16 + l16][nt * 16 + quad * 4] = pk;
        }
        const bf16x8 pbB0 = *(const bf16x8*)&ps[w * 16 + l16][quad * 8];
        const bf16x8 pbB1 = *(const bf16x8*)&ps[w * 16 + l16][32 + quad * 8];

        // ---- PV: each V^T frag read once, used by both sub-tiles ----
        #pragma unroll
        for (int nt = 0; nt < 4; ++nt) {
            const bf16x8 va0 = *(const bf16x8*)&vt[cur][nt * 16 + l16][quad * 8];
            const bf16x8 va1 = *(const bf16x8*)&vt[cur][nt * 16 + l16][32 + quad * 8];
            OsA[nt] = MFMA16(va0, pbA0, OsA[nt]);
            OsA[nt] = MFMA16(va1, pbA1, OsA[nt]);
            OsB[nt] = MFMA16(va0, pbB0, OsB[nt]);
            OsB[nt] = MFMA16(va1, pbB1, OsB[nt]);
        }
        __syncthreads();
    }

    // ---- epilogue: lsum reduce, assemble in ps, add rbuf, b128 stores ----
    // Global row = qA + r (qA is the wave base; NO lane term -- r7 bug was -l16)
    esumA += __shfl_xor(esumA, 16, 64);
    esumA += __shfl_xor(esumA, 32, 64);
    esumB += __shfl_xor(esumB, 16, 64);
    esumB += __shfl_xor(esumB, 32, 64);
    const float invlA = 1.0f / esumA;
    const float invlB = 1.0f / esumB;
    const int erow = lane >> 3, ec8 = lane & 7;

    #pragma unroll
    for (int nt = 0; nt < 4; ++nt) {
        bf16x4 ov;
        #pragma unroll
        for (int r = 0; r < 4; ++r) ov[r] = (__bf16)(OsA[nt][r] * invlA);
        *(bf16x4*)&ps[w * 16 + l16][nt * 16 + quad * 4] = ov;
    }
    #pragma unroll
    for (int i = 0; i < 2; ++i) {
        const int r = erow + i * 8;
        const size_t goff = ((size_t)(n * L_ + qA + r)) * E_ + h * 64 + ec8 * 8;
        union { float4 f; __bf16 hv[8]; } ua, ub, uo;
        ua.f = *(const float4*)&ps[w * 16 + r][ec8 * 8];
        ub.f = *(const float4*)(rbuf + goff);
        #pragma unroll
        for (int j = 0; j < 8; ++j)
            uo.hv[j] = (__bf16)((float)ua.hv[j] + (float)ub.hv[j]);
        *(float4*)(attnA + goff) = uo.f;
    }
    #pragma unroll
    for (int nt = 0; nt < 4; ++nt) {
        bf16x4 ov;
        #pragma unroll
        for (int r = 0; r < 4; ++r) ov[r] = (__bf16)(OsB[nt][r] * invlB);
        *(bf16x4*)&ps[w * 16 + l16][nt * 16 + quad * 4] = ov;
    }
    #pragma unroll
    for (int i = 0; i < 2; ++i) {
        const int r = erow + i * 8;
        const size_t goff = ((size_t)(n * L_ + qA + 128 + r)) * E_ + h * 64 + ec8 * 8;
        union { float4 f; __bf16 hv[8]; } ua, ub, uo;
        ua.f = *(const float4*)&ps[w * 16 + r][ec8 * 8];
        ub.f = *(const float4*)(rbuf + goff);
        #pragma unroll
        for (int j = 0; j < 8; ++j)
            uo.hv[j] = (__bf16)((float)ua.hv[j] + (float)ub.hv[j]);
        *(float4*)(attnA + goff) = uo.f;
    }
}

// ---------------------------------------------------------------------------
// proj: out (8192 x 1024) f32 = attnA (bf16) @ Wo^T (bf16) + bo.
// 128x128 C tile, BK=64, global_load_lds width-16 staging.
// ---------------------------------------------------------------------------
__global__ __launch_bounds__(256) void proj_kernel(
    const __bf16* __restrict__ A, const __bf16* __restrict__ W,
    const float* __restrict__ bo, float* __restrict__ out)
{
    const int bid = blockIdx.x;
    const int rt = bid >> 3, ct = bid & 7;
    const int r0 = rt * 128, c0 = ct * 128;
    const int t = threadIdx.x, w = t >> 6, lane = t & 63;
    const int quad = lane >> 4, l16 = lane & 15;
    const int wm = w >> 1, wn = w & 1;

    __shared__ __bf16 As[128 * 64];
    __shared__ __bf16 Bs[128 * 64];

    f32x4 acc[16];
    const f32x4 zero4 = {0.f, 0.f, 0.f, 0.f};
    #pragma unroll
    for (int i = 0; i < 16; ++i) acc[i] = zero4;

    const int lrow = lane >> 3, lcg = lane & 7;

    for (int kt = 0; kt < 16; ++kt) {
        const int e0 = kt * 64;
        __syncthreads();
        #pragma unroll
        for (int i = 0; i < 4; ++i) {
            const int chunk = w * 4 + i;
            const int row = chunk * 8 + lrow;
            const __bf16* ga = A + (size_t)(r0 + row) * E_ + e0 + lcg * 8;
            const __bf16* gb = W + (size_t)(c0 + row) * E_ + e0 + lcg * 8;
            __builtin_amdgcn_global_load_lds(
                (const __attribute__((address_space(1))) void*)ga,
                (__attribute__((address_space(3))) void*)&As[chunk * 512], 16, 0, 0);
            __builtin_amdgcn_global_load_lds(
                (const __attribute__((address_space(1))) void*)gb,
                (__attribute__((address_space(3))) void*)&Bs[chunk * 512], 16, 0, 0);
        }
        __syncthreads();
        #pragma unroll
        for (int c = 0; c < 2; ++c) {
            bf16x8 am[4], bn[4];
            #pragma unroll
            for (int i = 0; i < 4; ++i) {
                am[i] = *(const bf16x8*)&As[(wm * 64 + i * 16 + l16) * 64 + c * 32 + quad * 8];
                bn[i] = *(const bf16x8*)&Bs[(wn * 64 + i * 16 + l16) * 64 + c * 32 + quad * 8];
            }
            #pragma unroll
            for (int i = 0; i < 4; ++i)
                #pragma unroll
                for (int j = 0; j < 4; ++j)
                    acc[i * 4 + j] = MFMA16(am[i], bn[j], acc[i * 4 + j]);
        }
    }

    #pragma unroll
    for (int i = 0; i < 4; ++i)
        #pragma unroll
        for (int j = 0; j < 4; ++j) {
            const int col = c0 + wn * 64 + j * 16 + l16;
            const float bb = bo[col];
            #pragma unroll
            for (int r = 0; r < 4; ++r)
                out[(size_t)(r0 + wm * 64 + i * 16 + quad * 4 + r) * E_ + col] =
                    acc[i * 4 + j][r] + bb;
        }
}

// ---------------------------------------------------------------------------
extern "C" void kernel_launch(void* const* d_in, const int* in_sizes, int n_in,
                              void* d_out, int out_size, void* d_ws, size_t ws_size,
                              hipStream_t stream)
{
    const float* x    = (const float*)d_in[0];
    const float* Wq   = (const float*)d_in[1];
    const float* bq   = (const float*)d_in[2];
    const float* Wk   = (const float*)d_in[3];
    const float* bk   = (const float*)d_in[4];
    const float* Wv   = (const float*)d_in[5];
    const float* bv   = (const float*)d_in[6];
    const float* Erel = (const float*)d_in[7];
    const float* Wo   = (const float*)d_in[8];
    const float* bo   = (const float*)d_in[9];
    float* out = (float*)d_out;

    char* p = (char*)d_ws;
    __bf16* qbf   = (__bf16*)p; p += (size_t)N_ * L_ * H_ * D_ * 2;  // 16 MB
    __bf16* kbf   = (__bf16*)p; p += (size_t)N_ * L_ * H_ * D_ * 2;  // scaled K
    __bf16* vbf   = (__bf16*)p; p += (size_t)N_ * L_ * H_ * D_ * 2;
    __bf16* vtrb  = (__bf16*)p; p += (size_t)N_ * L_ * H_ * D_ * 2;  // V^T
    __bf16* attnA = (__bf16*)p; p += (size_t)N_ * L_ * E_ * 2;       // 16 MB
    __bf16* rbuf  = (__bf16*)p; p += (size_t)N_ * L_ * E_ * 2;       // 16 MB
    __bf16* wobf  = (__bf16*)p; p += (size_t)E_ * E_ * 2;            // 2 MB
    __bf16* erbf  = (__bf16*)p; p += (size_t)L_ * D_ * 2;            // 128 KB

    prep_kernel<<<1088, 256, 0, stream>>>(Wo, Erel, wobf, erbf);
    qkv_kernel<<<(N_ * L_ * H_) / 64, 256, 0, stream>>>(x, Wq, bq, Wk, bk, Wv, bv,
                                                        qbf, kbf, vbf);
    vtr_kernel<<<N_ * H_ * (L_ / 64), 256, 0, stream>>>(vbf, vtrb);
    rel_kernel<<<512, 512, 0, stream>>>(qbf, vtrb, erbf, rbuf);
    flash_kernel<<<512, 512, 0, stream>>>(qbf, kbf, vtrb, rbuf, attnA);
    proj_kernel<<<(N_ * L_ / 128) * (E_ / 128), 256, 0, stream>>>(attnA, wobf, bo, out);
}